// Round 6
// baseline (4384.027 us; speedup 1.0000x reference)
//
#include <hip/hip_runtime.h>
#include <math.h>

#define B_ 16
#define N_ 2048
#define M_ 2048
#define ITERS_ 100
#define RCH_ 32
#define NCH_ (N_ / RCH_)            // 64 chunks
// (1/eps)*log2(e), eps = 0.1
#define SCALE_ 14.426950408889634f
// T' = 2^(SHIFT_ - SCALE_*C): C in [0,1) -> T' in [0.74, 16384], all normal fp16.
// The 2^SHIFT_ scale cancels identically between g' = p'/sum(F*T') and
// F = q'/sum(g'*T') (verified by scale-tracking: F-hat == F-true).
#define SHIFT_ 14.0f

typedef float f4 __attribute__((ext_vector_type(4)));
typedef _Float16 h2 __attribute__((ext_vector_type(2)));
typedef _Float16 h8 __attribute__((ext_vector_type(8)));

#if defined(__has_builtin)
#if __has_builtin(__builtin_amdgcn_fdot2)
#define FDOT2_(a, b, c) __builtin_amdgcn_fdot2((a), (b), (c), false)
#endif
#endif
#ifndef FDOT2_
#define FDOT2_(a, b, c) \
  ((c) + (float)(a).x * (float)(b).x + (float)(a).y * (float)(b).y)
#endif

// One fused Sinkhorn iteration in the factorized exp-domain:
//   g[n] = p'[n] / sum_m F[m]*t[n,m],   t = 2^(-SCALE_*C)
//   psum[s][b][m] = sum_{n in chunk s} g[n]*t[n,m]   (raw, no F factor)
// V=0: first iter — reads fp32 C, F==1, writes fp16 T' (scaled).
// V=1: hot iters  — reads fp16 T', F packed to half2, fdot2 row sums.
// V=2: last iter  — reads fp32 C (exact), F fp32, writes true g.
// Block (b,s): rows [s*32, s*32+32); 4 waves x 8 rows; lane owns cols
// {k*512 + 8*lane + j : k=0..3, j=0..7} (16B loads).
template <int V>
__global__ __launch_bounds__(256, 4) void sink_iter(
    const float* __restrict__ C, _Float16* __restrict__ T,
    const float* __restrict__ p, const float* __restrict__ F_arr,
    float* __restrict__ psum, float* __restrict__ g_out) {
  __shared__ float lds[4][M_];  // 32 KB
  const int tid = threadIdx.x;
  const int lane = tid & 63, w = tid >> 6;
  const int bid = blockIdx.x;
  const int b = bid >> 6, s = bid & (NCH_ - 1);

  h2 Fh[16];   // V==1
  f4 F32[8];   // V==2
  if (V == 1) {
    const f4* Fp = (const f4*)(F_arr + (size_t)b * M_);
#pragma unroll
    for (int k = 0; k < 4; k++) {
      f4 a = Fp[k * 128 + 2 * lane];
      f4 c = Fp[k * 128 + 2 * lane + 1];
      Fh[k * 4 + 0] = h2{(_Float16)a.x, (_Float16)a.y};
      Fh[k * 4 + 1] = h2{(_Float16)a.z, (_Float16)a.w};
      Fh[k * 4 + 2] = h2{(_Float16)c.x, (_Float16)c.y};
      Fh[k * 4 + 3] = h2{(_Float16)c.z, (_Float16)c.w};
    }
  }
  if (V == 2) {
    const f4* Fp = (const f4*)(F_arr + (size_t)b * M_);
#pragma unroll
    for (int k = 0; k < 4; k++) {
      F32[2 * k] = Fp[k * 128 + 2 * lane];
      F32[2 * k + 1] = Fp[k * 128 + 2 * lane + 1];
    }
  }

  f4 sr[8];
#pragma unroll
  for (int k = 0; k < 8; k++) sr[k] = f4{0.f, 0.f, 0.f, 0.f};

  const int row0 = s * RCH_ + w * 8;
  const float* prow = p + (size_t)b * N_ + row0;

  for (int i = 0; i < 8; i++) {
    const size_t roff = ((size_t)b * N_ + row0 + i) * (size_t)M_;
    float rs = 0.f;
    if (V == 1) {
      h8 t[4];
      const h8* Tr = (const h8*)(T + roff);
#pragma unroll
      for (int k = 0; k < 4; k++) t[k] = Tr[k * 64 + lane];
#pragma unroll
      for (int k = 0; k < 4; k++) {
        const h2* tp = (const h2*)&t[k];
#pragma unroll
        for (int j = 0; j < 4; j++) rs = FDOT2_(tp[j], Fh[k * 4 + j], rs);
      }
#pragma unroll
      for (int o = 32; o; o >>= 1) rs += __shfl_xor(rs, o, 64);
      float g = (prow[i] + 1e-8f) / rs;
#pragma unroll
      for (int k = 0; k < 4; k++) {
        const h2* tp = (const h2*)&t[k];
#pragma unroll
        for (int j = 0; j < 2; j++) {
          h2 p0 = tp[2 * j], p1 = tp[2 * j + 1];
          sr[2 * k + j].x += g * (float)p0.x;
          sr[2 * k + j].y += g * (float)p0.y;
          sr[2 * k + j].z += g * (float)p1.x;
          sr[2 * k + j].w += g * (float)p1.y;
        }
      }
    } else {
      f4 tv[8];
      const f4* Cr = (const f4*)(C + roff);
#pragma unroll
      for (int k = 0; k < 4; k++) {
#pragma unroll
        for (int j = 0; j < 2; j++) {
          f4 c = Cr[k * 128 + 2 * lane + j];
          f4 t;
          if (V == 0) {
            t.x = exp2f(fmaf(-SCALE_, c.x, SHIFT_));
            t.y = exp2f(fmaf(-SCALE_, c.y, SHIFT_));
            t.z = exp2f(fmaf(-SCALE_, c.z, SHIFT_));
            t.w = exp2f(fmaf(-SCALE_, c.w, SHIFT_));
            rs += (t.x + t.y) + (t.z + t.w);
          } else {
            t.x = exp2f(-SCALE_ * c.x);
            t.y = exp2f(-SCALE_ * c.y);
            t.z = exp2f(-SCALE_ * c.z);
            t.w = exp2f(-SCALE_ * c.w);
            f4 e = F32[2 * k + j] * t;
            rs += (e.x + e.y) + (e.z + e.w);
          }
          tv[2 * k + j] = t;
        }
      }
      if (V == 0) {  // persist fp16 T' for the hot iterations
        h8* Tw = (h8*)(T + roff);
#pragma unroll
        for (int k = 0; k < 4; k++) {
          h8 ov;
          f4 t0 = tv[2 * k], t1 = tv[2 * k + 1];
          ov[0] = (_Float16)t0.x; ov[1] = (_Float16)t0.y;
          ov[2] = (_Float16)t0.z; ov[3] = (_Float16)t0.w;
          ov[4] = (_Float16)t1.x; ov[5] = (_Float16)t1.y;
          ov[6] = (_Float16)t1.z; ov[7] = (_Float16)t1.w;
          Tw[k * 64 + lane] = ov;
        }
      }
#pragma unroll
      for (int o = 32; o; o >>= 1) rs += __shfl_xor(rs, o, 64);
      float g = (prow[i] + 1e-8f) / rs;
      if (V == 2 && lane == 0) g_out[(size_t)b * N_ + row0 + i] = g;
#pragma unroll
      for (int k = 0; k < 8; k++) sr[k] += tv[k] * g;
    }
  }

  // cross-wave column reduction -> psum (raw colsums, no F factor)
#pragma unroll
  for (int k = 0; k < 4; k++) {
    *(f4*)&lds[w][k * 512 + 8 * lane] = sr[2 * k];
    *(f4*)&lds[w][k * 512 + 8 * lane + 4] = sr[2 * k + 1];
  }
  __syncthreads();
  {
    int base = w * 512 + 8 * lane;
    f4 a0 = *(const f4*)&lds[0][base] + *(const f4*)&lds[1][base] +
            *(const f4*)&lds[2][base] + *(const f4*)&lds[3][base];
    f4 a1 = *(const f4*)&lds[0][base + 4] + *(const f4*)&lds[1][base + 4] +
            *(const f4*)&lds[2][base + 4] + *(const f4*)&lds[3][base + 4];
    float* po = &psum[(size_t)(s * B_ + b) * M_ + base];
    *(f4*)po = a0;
    *(f4*)(po + 4) = a1;
  }
}

// F update: psum excludes F, so the column constraint F*colsum_raw = q'
// gives an ASSIGNMENT (the R5 multiplicative update was the NaN bug):
//   F[m] = q'[m] / sum_s psum[s][m]
__global__ __launch_bounds__(256) void lfk_kernel(
    const float* __restrict__ psum, const float* __restrict__ q,
    float* __restrict__ F) {
  int gid = blockIdx.x * 256 + threadIdx.x;  // f4 granule over B_*M_/4
  int b = gid >> 9;
  int mg = gid & 511;
  f4 S = f4{0.f, 0.f, 0.f, 0.f};
  const f4* P = (const f4*)psum;
#pragma unroll 8
  for (int s = 0; s < NCH_; s++)
    S += P[(size_t)(s * B_ + b) * (M_ / 4) + mg];
  f4 qq = ((const f4*)q)[gid];
  f4 r;
  r.x = (qq.x + 1e-8f) / S.x;
  r.y = (qq.y + 1e-8f) / S.y;
  r.z = (qq.z + 1e-8f) / S.z;
  r.w = (qq.w + 1e-8f) / S.w;
  ((f4*)F)[gid] = r;
}

// pi = g[n] * F[m] * 2^(-SCALE_*C)  (exact fp32 C)
__global__ __launch_bounds__(256) void pi_kernel(
    const float* __restrict__ C, const float* __restrict__ g_arr,
    const float* __restrict__ F_arr, float* __restrict__ out) {
  int bid = blockIdx.x;
  int tid = threadIdx.x;
  int b = bid >> 11;
  float gg = g_arr[bid];
  const f4* Cr = (const f4*)(C + (size_t)bid * M_);
  const f4* Fr = (const f4*)(F_arr + (size_t)b * M_);
  f4* Or = (f4*)(out + (size_t)bid * M_);
#pragma unroll
  for (int k = 0; k < 2; k++) {
    int i = tid + (k << 8);
    f4 c = __builtin_nontemporal_load(&Cr[i]);
    f4 f = Fr[i];
    f4 r;
    r.x = gg * f.x * exp2f(-SCALE_ * c.x);
    r.y = gg * f.y * exp2f(-SCALE_ * c.y);
    r.z = gg * f.z * exp2f(-SCALE_ * c.z);
    r.w = gg * f.w * exp2f(-SCALE_ * c.w);
    __builtin_nontemporal_store(r, &Or[i]);
  }
}

extern "C" void kernel_launch(void* const* d_in, const int* in_sizes, int n_in,
                              void* d_out, int out_size, void* d_ws, size_t ws_size,
                              hipStream_t stream) {
  const float* p = (const float*)d_in[0];
  const float* q = (const float*)d_in[1];
  const float* C = (const float*)d_in[2];
  float* out = (float*)d_out;

  const size_t Telems = (size_t)B_ * N_ * M_;      // 67.1M halves = 134 MB
  const size_t psz = (size_t)NCH_ * B_ * M_;       // 2,097,152 floats = 8 MB
  const size_t gsz = (size_t)B_ * N_;
  const size_t fsz = (size_t)B_ * M_;
  const size_t need_all =
      Telems * sizeof(_Float16) + (psz + gsz + fsz) * sizeof(float);

  _Float16* T;
  float *psum, *g_arr, *F_arr;
  if (ws_size >= need_all) {
    T = (_Float16*)d_ws;
    psum = (float*)(T + Telems);
    g_arr = psum + psz;
    F_arr = g_arr + gsz;
  } else {
    // g,F in ws (256 KB); T in d_out front (134 MB), psum in d_out tail (8 MB).
    // T is last read at iter 98, psum last read by the final lfk; pi_kernel
    // then rewrites all of d_out reading only C/g/F -> safe, deterministic.
    g_arr = (float*)d_ws;
    F_arr = g_arr + gsz;
    T = (_Float16*)d_out;
    psum = out + ((size_t)out_size - psz);
  }

  sink_iter<0><<<B_ * NCH_, 256, 0, stream>>>(C, T, p, F_arr, psum, g_arr);
  lfk_kernel<<<B_ * M_ / 1024, 256, 0, stream>>>(psum, q, F_arr);
  for (int t = 1; t < ITERS_ - 1; ++t) {
    sink_iter<1><<<B_ * NCH_, 256, 0, stream>>>(C, T, p, F_arr, psum, g_arr);
    lfk_kernel<<<B_ * M_ / 1024, 256, 0, stream>>>(psum, q, F_arr);
  }
  sink_iter<2><<<B_ * NCH_, 256, 0, stream>>>(C, T, p, F_arr, psum, g_arr);
  lfk_kernel<<<B_ * M_ / 1024, 256, 0, stream>>>(psum, q, F_arr);
  pi_kernel<<<B_ * N_, 256, 0, stream>>>(C, g_arr, F_arr, out);
}